// Round 5
// baseline (171.422 us; speedup 1.0000x reference)
//
#include <hip/hip_runtime.h>
#include <hip/hip_bf16.h>
#include <stdint.h>

typedef __attribute__((ext_vector_type(8))) short bf16x8;
typedef __attribute__((ext_vector_type(8))) short short8;
typedef __attribute__((ext_vector_type(4))) float f32x4;

#define M_DIM 512
#define N_DIM 4096
#define K_DIM 11008
#define KSTEPS 172   // K_DIM / 64

#define GLOBAL_AS(p) ((const __attribute__((address_space(1))) void*)(p))
#define LDS_AS(p)    ((__attribute__((address_space(3))) void*)(p))

// round-to-nearest-even fp32 -> bf16 bits
__device__ __forceinline__ short f2bf(float f) {
    unsigned u = __float_as_uint(f);
    unsigned r = u + 0x7fff + ((u >> 16) & 1);
    return (short)(r >> 16);
}

__device__ __forceinline__ unsigned cvt_pk_bf16(float lo, float hi) {
    unsigned r;
    asm("v_cvt_pk_bf16_f32 %0, %1, %2" : "=v"(r) : "v"(lo), "v"(hi));
    return r;
}

__device__ __forceinline__ float dpp_xor1_min(float v) {
    int r = __builtin_amdgcn_mov_dpp(__float_as_int(v), 0xB1, 0xf, 0xf, true);
    return fminf(v, __int_as_float(r));
}
__device__ __forceinline__ float dpp_xor1_max(float v) {
    int r = __builtin_amdgcn_mov_dpp(__float_as_int(v), 0xB1, 0xf, 0xf, true);
    return fmaxf(v, __int_as_float(r));
}

__device__ __forceinline__ void fence_bar() {
    asm volatile("" ::: "memory");
    __builtin_amdgcn_s_barrier();
    asm volatile("" ::: "memory");
}
#define LGKM0() asm volatile("s_waitcnt lgkmcnt(0)" ::: "memory")
#define VMCNT(n) asm volatile("s_waitcnt vmcnt(" #n ")" ::: "memory")

// ---------------- Kernel 1: x fp32 -> bf16 ----------------
__global__ __launch_bounds__(256) void conv_x(const float* __restrict__ x, short* __restrict__ xb) {
    const long long total = (long long)M_DIM * K_DIM;
    for (long long e0 = ((long long)blockIdx.x * 256 + threadIdx.x) * 8;
         e0 < total;
         e0 += (long long)gridDim.x * 256 * 8) {
        const float4* p = (const float4*)(x + e0);
        float4 v0 = p[0];
        float4 v1 = p[1];
        short8 s;
        s[0] = f2bf(v0.x); s[1] = f2bf(v0.y); s[2] = f2bf(v0.z); s[3] = f2bf(v0.w);
        s[4] = f2bf(v1.x); s[5] = f2bf(v1.y); s[6] = f2bf(v1.z); s[7] = f2bf(v1.w);
        *(short8*)(xb + e0) = s;
    }
}

// ---------------- Kernel 2: fused fake-quant + 256x256 8-phase bf16 GEMM, split-K ----------------
// A = xb [M,K] bf16 via global_load_lds (XOR-swizzled source).
// B = W [N,K] fp32; thread owns HALF a row's K-group (32 floats). Reduce = pure-VALU tree +
// one DPP quad_perm xor1 (lanes 2k<->2k+1). Quant spread: P0 reduce+div, P1/P2 16 elems each.
// Two named reg sets (R0/R1) over a 2-tile-unrolled loop. 512 thr = 8 waves; wave C = 128x64.

template<int QD>
__device__ __forceinline__ void phase_reads(const short* __restrict__ Asd,
                                            const short* __restrict__ Bsd,
                                            int arow, int brow, int qb,
                                            bf16x8 (&af)[2][2], bf16x8 (&bfr)[2][4]) {
    if (QD == 0) {
        #pragma unroll
        for (int ks = 0; ks < 2; ++ks)
            #pragma unroll
            for (int fn = 0; fn < 4; ++fn) {
                const int r = brow + fn * 16;
                bfr[ks][fn] = *(const bf16x8*)&Bsd[r * 64 + (((ks * 4 + qb) ^ (r & 7)) * 8)];
            }
    }
    #pragma unroll
    for (int ks = 0; ks < 2; ++ks)
        #pragma unroll
        for (int j = 0; j < 2; ++j) {
            const int r = arow + (QD * 2 + j) * 16;
            af[ks][j] = *(const bf16x8*)&Asd[r * 64 + (((ks * 4 + qb) ^ (r & 7)) * 8)];
        }
}

template<int QD>
__device__ __forceinline__ void phase_mfma(const bf16x8 (&af)[2][2], const bf16x8 (&bfr)[2][4],
                                           f32x4 (&acc)[8][4]) {
    __builtin_amdgcn_s_setprio(1);
    #pragma unroll
    for (int ks = 0; ks < 2; ++ks)
        #pragma unroll
        for (int j = 0; j < 2; ++j)
            #pragma unroll
            for (int fn = 0; fn < 4; ++fn)
                acc[QD * 2 + j][fn] = __builtin_amdgcn_mfma_f32_16x16x32_bf16(
                    af[ks][j], bfr[ks][fn], acc[QD * 2 + j][fn], 0, 0, 0);
    __builtin_amdgcn_s_setprio(0);
}

__global__ __launch_bounds__(512, 2) void gemm_fq(const short* __restrict__ A,
                                                  const float* __restrict__ W,
                                                  unsigned short* __restrict__ P,
                                                  int spb) {
    __shared__ short As[2][256 * 64];
    __shared__ short Bs[2][256 * 64];
    const int tid  = threadIdx.x;
    const int lane = tid & 63;
    const int w    = tid >> 6;
    const int wr   = w >> 2;     // 0..1
    const int wc   = w & 3;      // 0..3
    const int m0   = blockIdx.y * 256;
    const int n0   = blockIdx.x * 256;
    const int kt0  = blockIdx.z * spb;
    const int kt1  = min(kt0 + spb, KSTEPS);   // (kt1-kt0) even, >= 2

    const int srow = tid >> 3;                       // 0..63  (A staging)
    const int sswz = (tid & 7) ^ (srow & 7);         // A staging source swizzle
    const int rQ   = tid >> 1;                       // 0..255 (B row)
    const int hQ   = tid & 1;                        // half of the 64-group (32 floats)
    const int arow = wr * 128 + (lane & 15);
    const int brow = wc * 64 + (lane & 15);
    const int qb   = lane >> 4;

    f32x4  acc[8][4] = {};
    bf16x8 bfr[2][4];
    bf16x8 af[2][2];
    float4 R0[8], R1[8];                 // two B staging sets, static indexing
    float scale, rs, zp, qlo, qhi;       // per-tile quant params (computed P0)

    auto stageA = [&](int d, int h, int kt) {
        #pragma unroll
        for (int l = 0; l < 2; ++l) {
            __builtin_amdgcn_global_load_lds(
                GLOBAL_AS(A + (size_t)(m0 + h * 128 + l * 64 + srow) * K_DIM + kt * 64 + sswz * 8),
                LDS_AS(&As[d][(h * 128 + l * 64 + w * 8) * 64]), 16, 0, 0);
        }
    };
    auto loadR = [&](float4 (&dst)[8], int half, int kt) {
        const float4* src = (const float4*)(W + (size_t)(n0 + rQ) * K_DIM + kt * 64 + hQ * 32 + half * 16);
        #pragma unroll
        for (int j = 0; j < 4; ++j) dst[half * 4 + j] = src[j];
    };
    auto reduceR = [&](const float4 (&R)[8]) {
        float mns[8], mxs[8];
        #pragma unroll
        for (int i = 0; i < 8; ++i) {
            mns[i] = fminf(fminf(R[i].x, R[i].y), fminf(R[i].z, R[i].w));
            mxs[i] = fmaxf(fmaxf(R[i].x, R[i].y), fmaxf(R[i].z, R[i].w));
        }
        #pragma unroll
        for (int st = 4; st >= 1; st >>= 1)
            #pragma unroll
            for (int i = 0; i < st; ++i) {
                mns[i] = fminf(mns[i], mns[i + st]);
                mxs[i] = fmaxf(mxs[i], mxs[i + st]);
            }
        float mn = dpp_xor1_min(mns[0]);
        float mx = dpp_xor1_max(mxs[0]);
        float range = fmaxf(mx - mn, 1e-5f);
        scale = range * (1.0f / 15.0f);
        rs    = 1.0f / scale;            // one precise div per thread per tile
        zp    = rintf(-mn * rs);
        qlo   = -zp;
        qhi   = 15.0f - zp;
    };
    // quantize 16 elems (half16 in {0,1}) of R into two bf16x8 slots of BsF
    auto quantHalf = [&](const float4 (&R)[8], int half16, short* BsF) {
        #pragma unroll
        for (int pairq = 0; pairq < 2; ++pairq) {
            const float4 va = R[half16 * 4 + pairq * 2 + 0];
            const float4 vb = R[half16 * 4 + pairq * 2 + 1];
            float q[8];
            const float* pv = (const float*)&va;
            #pragma unroll
            for (int j = 0; j < 4; ++j)
                q[j] = fminf(fmaxf(rintf(pv[j] * rs), qlo), qhi) * scale;
            pv = (const float*)&vb;
            #pragma unroll
            for (int j = 0; j < 4; ++j)
                q[4 + j] = fminf(fmaxf(rintf(pv[j] * rs), qlo), qhi) * scale;
            union { unsigned u[4]; short8 s; } pk;
            #pragma unroll
            for (int j = 0; j < 4; ++j)
                pk.u[j] = cvt_pk_bf16(q[2 * j], q[2 * j + 1]);
            const int s = hQ * 4 + half16 * 2 + pairq;    // 8-elem slot 0..7
            *(short8*)&BsF[rQ * 64 + ((s ^ (rQ & 7)) * 8)] = pk.s;
        }
    };

    // ---- prologue: quant tile kt0 -> Bs[0]; A(kt0) -> As[0]; load R1 <- B(kt0+1) ----
    loadR(R0, 0, kt0); loadR(R0, 1, kt0);
    stageA(0, 0, kt0); stageA(0, 1, kt0);
    VMCNT(4);                                   // R0 landed (A x4 outstanding)
    reduceR(R0);
    quantHalf(R0, 0, Bs[0]);
    quantHalf(R0, 1, Bs[0]);
    loadR(R1, 0, kt0 + 1); loadR(R1, 1, kt0 + 1);
    VMCNT(8);                                   // A(kt0) landed (R1 x8 outstanding)
    LGKM0();
    fence_bar();

    for (int t = kt0; t < kt1; t += 2) {
        const int tb  = t + 1;
        const int ta2 = (t + 2 < kt1) ? t + 2 : kt1 - 1;   // B loads during ta
        const int tb2 = (t + 3 < kt1) ? t + 3 : kt1 - 1;   // B loads during tb
        const int tAn = (t + 2 < kt1) ? t + 2 : tb;        // A stage during tb (dummy on last)

        // ======== tile ta: compute As[0]/Bs[0]; quant R1 -> Bs[1]; load R0 <- B(ta2) ========
        // P0
        phase_reads<0>(As[0], Bs[0], arow, brow, qb, af, bfr);
        VMCNT(0);                        // R1 fully landed
        reduceR(R1);
        stageA(1, 0, tb);
        loadR(R0, 0, ta2);
        fence_bar(); LGKM0();
        phase_mfma<0>(af, bfr, acc);
        fence_bar();
        // P1
        phase_reads<1>(As[0], Bs[0], arow, brow, qb, af, bfr);
        quantHalf(R1, 0, Bs[1]);
        stageA(1, 1, tb);
        loadR(R0, 1, ta2);
        fence_bar(); LGKM0();
        phase_mfma<1>(af, bfr, acc);
        fence_bar();
        // P2
        phase_reads<2>(As[0], Bs[0], arow, brow, qb, af, bfr);
        quantHalf(R1, 1, Bs[1]);
        fence_bar(); LGKM0();
        phase_mfma<2>(af, bfr, acc);
        fence_bar();
        // P3
        phase_reads<3>(As[0], Bs[0], arow, brow, qb, af, bfr);
        fence_bar(); LGKM0();
        phase_mfma<3>(af, bfr, acc);
        VMCNT(4);                        // A(tb) landed (last R0 batch outstanding)
        fence_bar();

        // ======== tile tb: compute As[1]/Bs[1]; quant R0 -> Bs[0]; load R1 <- B(tb2) ========
        // P0
        phase_reads<0>(As[1], Bs[1], arow, brow, qb, af, bfr);
        VMCNT(0);                        // R0 fully landed
        reduceR(R0);
        stageA(0, 0, tAn);
        loadR(R1, 0, tb2);
        fence_bar(); LGKM0();
        phase_mfma<0>(af, bfr, acc);
        fence_bar();
        // P1
        phase_reads<1>(As[1], Bs[1], arow, brow, qb, af, bfr);
        quantHalf(R0, 0, Bs[0]);
        stageA(0, 1, tAn);
        loadR(R1, 1, tb2);
        fence_bar(); LGKM0();
        phase_mfma<1>(af, bfr, acc);
        fence_bar();
        // P2
        phase_reads<2>(As[1], Bs[1], arow, brow, qb, af, bfr);
        quantHalf(R0, 1, Bs[0]);
        fence_bar(); LGKM0();
        phase_mfma<2>(af, bfr, acc);
        fence_bar();
        // P3
        phase_reads<3>(As[1], Bs[1], arow, brow, qb, af, bfr);
        fence_bar(); LGKM0();
        phase_mfma<3>(af, bfr, acc);
        VMCNT(4);                        // A(next) landed
        fence_bar();
    }

    VMCNT(0);   // drain dummy/tail loads

    unsigned short* out = P + (size_t)blockIdx.z * M_DIM * N_DIM;
    #pragma unroll
    for (int fm = 0; fm < 8; ++fm) {
        #pragma unroll
        for (int fn = 0; fn < 4; ++fn) {
            const int col  = n0 + wc * 64 + fn * 16 + (lane & 15);
            const int rowb = m0 + wr * 128 + fm * 16 + (lane >> 4) * 4;
            #pragma unroll
            for (int r = 0; r < 4; ++r) {
                out[(size_t)(rowb + r) * N_DIM + col] = (unsigned short)f2bf(acc[fm][fn][r]);
            }
        }
    }
}

// ---------------- Kernel 3: reduce bf16 split-K partials + bias ----------------
__global__ __launch_bounds__(256) void reduce_out(const unsigned short* __restrict__ P,
                                                  const float* __restrict__ bias,
                                                  float* __restrict__ out,
                                                  int splitk) {
    const size_t total = (size_t)M_DIM * N_DIM;
    for (size_t idx8 = ((size_t)blockIdx.x * 256 + threadIdx.x) * 8;
         idx8 < total;
         idx8 += (size_t)gridDim.x * 256 * 8) {
        const int col = (int)(idx8 % N_DIM);
        float s[8];
        {
            float4 b0 = *(const float4*)(bias + col);
            float4 b1 = *(const float4*)(bias + col + 4);
            s[0] = b0.x; s[1] = b0.y; s[2] = b0.z; s[3] = b0.w;
            s[4] = b1.x; s[5] = b1.y; s[6] = b1.z; s[7] = b1.w;
        }
        for (int sp = 0; sp < splitk; ++sp) {
            short8 p = *(const short8*)(P + (size_t)sp * total + idx8);
            #pragma unroll
            for (int j = 0; j < 8; ++j)
                s[j] += __uint_as_float(((unsigned)(unsigned short)p[j]) << 16);
        }
        float4 o0 = {s[0], s[1], s[2], s[3]};
        float4 o1 = {s[4], s[5], s[6], s[7]};
        *(float4*)(out + idx8) = o0;
        *(float4*)(out + idx8 + 4) = o1;
    }
}

extern "C" void kernel_launch(void* const* d_in, const int* in_sizes, int n_in,
                              void* d_out, int out_size, void* d_ws, size_t ws_size,
                              hipStream_t stream) {
    const float* x    = (const float*)d_in[0];
    const float* wgt  = (const float*)d_in[1];
    const float* bias = (const float*)d_in[2];
    float* out = (float*)d_out;

    char* ws = (char*)d_ws;
    const size_t xb_bytes = (size_t)M_DIM * K_DIM * 2;          // 11,272,192
    short* xb = (short*)ws;
    unsigned short* part = (unsigned short*)(ws + xb_bytes);

    const size_t per_split = (size_t)M_DIM * N_DIM * 2;         // 4 MiB (bf16)
    size_t avail = (ws_size > xb_bytes) ? (ws_size - xb_bytes) : 0;
    // largest splitk in [1,8] that fits, with even steps-per-split and every split >= 2 K-tiles
    int splitk = 1, spb = KSTEPS;
    for (int sk = 8; sk >= 1; --sk) {
        if ((size_t)sk * per_split > avail) continue;
        int s = (KSTEPS + sk - 1) / sk;
        if (s & 1) s++;
        int last = KSTEPS - (sk - 1) * s;
        if (last < 2) continue;
        splitk = sk; spb = s;
        break;
    }

    hipLaunchKernelGGL(conv_x, dim3(2048), dim3(256), 0, stream, x, xb);
    hipLaunchKernelGGL(gemm_fq, dim3(N_DIM / 256, M_DIM / 256, splitk), dim3(512), 0, stream,
                       xb, wgt, part, spb);
    hipLaunchKernelGGL(reduce_out, dim3(1024), dim3(256), 0, stream, part, bias, out, splitk);
}

// Round 6
// 141.196 us; speedup vs baseline: 1.2141x; 1.2141x over previous
//
#include <hip/hip_runtime.h>
#include <hip/hip_bf16.h>
#include <stdint.h>

typedef __attribute__((ext_vector_type(8))) short bf16x8;
typedef __attribute__((ext_vector_type(8))) short short8;
typedef __attribute__((ext_vector_type(4))) float f32x4;

#define M_DIM 512
#define N_DIM 4096
#define K_DIM 11008
#define KSTEPS 172   // K_DIM / 64

#define GLOBAL_AS(p) ((const __attribute__((address_space(1))) void*)(p))
#define LDS_AS(p)    ((__attribute__((address_space(3))) void*)(p))

// round-to-nearest-even fp32 -> bf16 bits
__device__ __forceinline__ short f2bf(float f) {
    unsigned u = __float_as_uint(f);
    unsigned r = u + 0x7fff + ((u >> 16) & 1);
    return (short)(r >> 16);
}

__device__ __forceinline__ unsigned cvt_pk_bf16(float lo, float hi) {
    unsigned r;
    asm("v_cvt_pk_bf16_f32 %0, %1, %2" : "=v"(r) : "v"(lo), "v"(hi));
    return r;
}

// lane 2k <-> 2k+1 exchange (pure VALU DPP quad_perm [1,0,3,2])
__device__ __forceinline__ float dpp_xor1(float v) {
    return __int_as_float(__builtin_amdgcn_mov_dpp(__float_as_int(v), 0xB1, 0xf, 0xf, true));
}

__device__ __forceinline__ void fence_bar() {
    asm volatile("" ::: "memory");
    __builtin_amdgcn_s_barrier();
    asm volatile("" ::: "memory");
}
#define LGKM0() asm volatile("s_waitcnt lgkmcnt(0)" ::: "memory")
#define VMCNT(n) asm volatile("s_waitcnt vmcnt(" #n ")" ::: "memory")

// ---------------- Kernel 1: x fp32 -> bf16 ----------------
__global__ __launch_bounds__(256) void conv_x(const float* __restrict__ x, short* __restrict__ xb) {
    const long long total = (long long)M_DIM * K_DIM;
    for (long long e0 = ((long long)blockIdx.x * 256 + threadIdx.x) * 8;
         e0 < total;
         e0 += (long long)gridDim.x * 256 * 8) {
        const float4* p = (const float4*)(x + e0);
        float4 v0 = p[0];
        float4 v1 = p[1];
        short8 s;
        s[0] = f2bf(v0.x); s[1] = f2bf(v0.y); s[2] = f2bf(v0.z); s[3] = f2bf(v0.w);
        s[4] = f2bf(v1.x); s[5] = f2bf(v1.y); s[6] = f2bf(v1.z); s[7] = f2bf(v1.w);
        *(short8*)(xb + e0) = s;
    }
}

// ---------------- Kernel 2: fused fake-quant + 128x128 bf16 GEMM, split-K ----------------
// 256 threads = 4 waves (2x2); wave tile 64x64 = 4x4 frags of mfma 16x16x32.
// A = xb [M,K] bf16, double-buffered LDS via global_load_lds (XOR-swizzled source).
// B = W [N,K] fp32, single reg set R[8] (thread = half a row's 64-group), quantized one
// iteration after load (DPP-xor1 pair reduce, no DS ops), written swizzled to single-buffer Bs.
// LDS = 2*16KB (A) + 16KB (B) = 48 KiB -> 2 blocks/CU. Partials bf16.
__global__ __launch_bounds__(256, 2) void gemm_fq(const short* __restrict__ A,
                                                  const float* __restrict__ W,
                                                  unsigned short* __restrict__ P,
                                                  int spb) {
    __shared__ short As[2][128 * 64];
    __shared__ short Bs[128 * 64];
    const int tid  = threadIdx.x;
    const int lane = tid & 63;
    const int w    = tid >> 6;
    const int wr   = w >> 1;     // 0..1
    const int wc   = w & 1;      // 0..1
    const int m0   = blockIdx.y * 128;
    const int n0   = blockIdx.x * 128;
    const int kt0  = blockIdx.z * spb;
    const int kt1  = min(kt0 + spb, KSTEPS);

    const int srow = lane >> 3;   // A staging: row within 8-row chunk
    const int slot = lane & 7;    // A staging: 8-elem slot
    const int rQ   = tid >> 1;    // 0..127 B row
    const int hQ   = tid & 1;     // half of the 64-elem group (32 floats)
    const int frA  = wr * 64 + (lane & 15);
    const int frB  = wc * 64 + (lane & 15);
    const int qb   = lane >> 4;

    f32x4  acc[4][4] = {};
    float4 R[8];                  // B staging, static indexing only

    auto stageA = [&](int d, int kt) {
        #pragma unroll
        for (int i = 0; i < 4; ++i) {
            const int rb  = (w * 4 + i) * 8;
            const int row = rb + srow;
            const int gcol = ((slot ^ (row & 7)) * 8);
            __builtin_amdgcn_global_load_lds(
                GLOBAL_AS(A + (size_t)(m0 + row) * K_DIM + kt * 64 + gcol),
                LDS_AS(&As[d][rb * 64]), 16, 0, 0);
        }
    };
    auto loadR = [&](int kt) {
        const float4* src = (const float4*)(W + (size_t)(n0 + rQ) * K_DIM + (size_t)kt * 64 + hQ * 32);
        #pragma unroll
        for (int j = 0; j < 8; ++j) R[j] = src[j];
    };
    auto quantB = [&]() {
        const float* pv = (const float*)&R[0];
        float mns[16], mxs[16];
        #pragma unroll
        for (int j = 0; j < 16; ++j) {
            mns[j] = fminf(pv[2 * j], pv[2 * j + 1]);
            mxs[j] = fmaxf(pv[2 * j], pv[2 * j + 1]);
        }
        #pragma unroll
        for (int st = 8; st >= 1; st >>= 1)
            #pragma unroll
            for (int j = 0; j < st; ++j) {
                mns[j] = fminf(mns[j], mns[j + st]);
                mxs[j] = fmaxf(mxs[j], mxs[j + st]);
            }
        float mn = fminf(mns[0], dpp_xor1(mns[0]));   // pair lanes share row rQ
        float mx = fmaxf(mxs[0], dpp_xor1(mxs[0]));
        float range = fmaxf(mx - mn, 1e-5f);
        float scale = range * (1.0f / 15.0f);
        float rs    = 1.0f / scale;   // one precise div per thread per tile
        // clamp is mathematically redundant: rint(mn*rs) = -zp, rint(mx*rs) <= 15-zp
        #pragma unroll
        for (int s4 = 0; s4 < 4; ++s4) {
            float q[8];
            #pragma unroll
            for (int j = 0; j < 8; ++j)
                q[j] = rintf(pv[s4 * 8 + j] * rs) * scale;
            union { unsigned u[4]; short8 s; } pk;
            #pragma unroll
            for (int j = 0; j < 4; ++j)
                pk.u[j] = cvt_pk_bf16(q[2 * j], q[2 * j + 1]);
            const int s = hQ * 4 + s4;   // 8-elem slot 0..7
            *(short8*)&Bs[rQ * 64 + ((s ^ (rQ & 7)) * 8)] = pk.s;
        }
    };

    // ---- prologue: queue = [R(kt0)(8), A(kt0)(4)] ----
    loadR(kt0);
    stageA(0, kt0);

    int par = 0;
    for (int t = kt0; t < kt1; ++t) {
        const int tn = (t + 1 < kt1) ? t + 1 : t;   // dummy refetch on last iter
        VMCNT(4);                 // R(t) landed (loaded one full iter ago); leaves [A(t)(4)]
        quantB();                 // R -> Bs (prev iter's Bs readers finished before prev barrier)
        loadR(tn);                // +8
        stageA(par ^ 1, tn);      // +4 ; queue [A(t)4, R(t+1)8, A(t+1)4]
        LGKM0();                  // quant ds_writes drained
        VMCNT(12);                // A(t) landed (staged one full iter ago)
        fence_bar();
        // ---- compute tile t from As[par] + Bs ----
        #pragma unroll
        for (int ks = 0; ks < 2; ++ks) {
            bf16x8 af[4], bfr[4];
            #pragma unroll
            for (int fm = 0; fm < 4; ++fm) {
                const int r = frA + fm * 16;
                af[fm] = *(const bf16x8*)&As[par][r * 64 + (((ks * 4 + qb) ^ (r & 7)) * 8)];
            }
            #pragma unroll
            for (int fn = 0; fn < 4; ++fn) {
                const int r = frB + fn * 16;
                bfr[fn] = *(const bf16x8*)&Bs[r * 64 + (((ks * 4 + qb) ^ (r & 7)) * 8)];
            }
            LGKM0();
            __builtin_amdgcn_sched_barrier(0);
            __builtin_amdgcn_s_setprio(1);
            #pragma unroll
            for (int fm = 0; fm < 4; ++fm)
                #pragma unroll
                for (int fn = 0; fn < 4; ++fn)
                    acc[fm][fn] = __builtin_amdgcn_mfma_f32_16x16x32_bf16(
                        af[fm], bfr[fn], acc[fm][fn], 0, 0, 0);
            __builtin_amdgcn_s_setprio(0);
        }
        fence_bar();
        par ^= 1;
    }

    VMCNT(0);   // drain dummy tail loads

    unsigned short* out = P + (size_t)blockIdx.z * M_DIM * N_DIM;
    #pragma unroll
    for (int fm = 0; fm < 4; ++fm) {
        #pragma unroll
        for (int fn = 0; fn < 4; ++fn) {
            const int col  = n0 + wc * 64 + fn * 16 + (lane & 15);
            const int rowb = m0 + wr * 64 + fm * 16 + (lane >> 4) * 4;
            #pragma unroll
            for (int r = 0; r < 4; ++r) {
                out[(size_t)(rowb + r) * N_DIM + col] = (unsigned short)f2bf(acc[fm][fn][r]);
            }
        }
    }
}

// ---------------- Kernel 3: reduce bf16 split-K partials + bias ----------------
__global__ __launch_bounds__(256) void reduce_out(const unsigned short* __restrict__ P,
                                                  const float* __restrict__ bias,
                                                  float* __restrict__ out,
                                                  int splitk) {
    const size_t total = (size_t)M_DIM * N_DIM;
    for (size_t idx8 = ((size_t)blockIdx.x * 256 + threadIdx.x) * 8;
         idx8 < total;
         idx8 += (size_t)gridDim.x * 256 * 8) {
        const int col = (int)(idx8 % N_DIM);
        float s[8];
        {
            float4 b0 = *(const float4*)(bias + col);
            float4 b1 = *(const float4*)(bias + col + 4);
            s[0] = b0.x; s[1] = b0.y; s[2] = b0.z; s[3] = b0.w;
            s[4] = b1.x; s[5] = b1.y; s[6] = b1.z; s[7] = b1.w;
        }
        for (int sp = 0; sp < splitk; ++sp) {
            short8 p = *(const short8*)(P + (size_t)sp * total + idx8);
            #pragma unroll
            for (int j = 0; j < 8; ++j)
                s[j] += __uint_as_float(((unsigned)(unsigned short)p[j]) << 16);
        }
        float4 o0 = {s[0], s[1], s[2], s[3]};
        float4 o1 = {s[4], s[5], s[6], s[7]};
        *(float4*)(out + idx8) = o0;
        *(float4*)(out + idx8 + 4) = o1;
    }
}

extern "C" void kernel_launch(void* const* d_in, const int* in_sizes, int n_in,
                              void* d_out, int out_size, void* d_ws, size_t ws_size,
                              hipStream_t stream) {
    const float* x    = (const float*)d_in[0];
    const float* wgt  = (const float*)d_in[1];
    const float* bias = (const float*)d_in[2];
    float* out = (float*)d_out;

    char* ws = (char*)d_ws;
    const size_t xb_bytes = (size_t)M_DIM * K_DIM * 2;          // 11,272,192
    short* xb = (short*)ws;
    unsigned short* part = (unsigned short*)(ws + xb_bytes);

    const size_t per_split = (size_t)M_DIM * N_DIM * 2;         // 4 MiB (bf16)
    size_t avail = (ws_size > xb_bytes) ? (ws_size - xb_bytes) : 0;
    int splitk = 4;                                             // 32x4x4 = 512 blocks = 2/CU
    while (splitk > 1 && (size_t)splitk * per_split > avail) splitk--;
    const int spb = (KSTEPS + splitk - 1) / splitk;             // 43 at splitk=4

    hipLaunchKernelGGL(conv_x, dim3(2048), dim3(256), 0, stream, x, xb);
    hipLaunchKernelGGL(gemm_fq, dim3(N_DIM / 128, M_DIM / 128, splitk), dim3(256), 0, stream,
                       xb, wgt, part, spb);
    hipLaunchKernelGGL(reduce_out, dim3(1024), dim3(256), 0, stream, part, bias, out, splitk);
}

// Round 7
// 98.613 us; speedup vs baseline: 1.7383x; 1.4318x over previous
//
#include <hip/hip_runtime.h>
#include <hip/hip_bf16.h>
#include <stdint.h>

typedef __attribute__((ext_vector_type(8))) short bf16x8;
typedef __attribute__((ext_vector_type(8))) short short8;
typedef __attribute__((ext_vector_type(4))) float f32x4;

#define M_DIM 512
#define N_DIM 4096
#define K_DIM 11008
#define KSTEPS 172   // K_DIM / 64

#define GLOBAL_AS(p) ((const __attribute__((address_space(1))) void*)(p))
#define LDS_AS(p)    ((__attribute__((address_space(3))) void*)(p))

// round-to-nearest-even fp32 -> bf16 bits
__device__ __forceinline__ short f2bf(float f) {
    unsigned u = __float_as_uint(f);
    unsigned r = u + 0x7fff + ((u >> 16) & 1);
    return (short)(r >> 16);
}

__device__ __forceinline__ unsigned cvt_pk_bf16(float lo, float hi) {
    unsigned r;
    asm("v_cvt_pk_bf16_f32 %0, %1, %2" : "=v"(r) : "v"(lo), "v"(hi));
    return r;
}

// quad_perm lane exchanges (pure VALU, no DS)
__device__ __forceinline__ float dpp_xor1(float v) {
    return __int_as_float(__builtin_amdgcn_mov_dpp(__float_as_int(v), 0xB1, 0xf, 0xf, true));
}
__device__ __forceinline__ float dpp_xor2(float v) {
    return __int_as_float(__builtin_amdgcn_mov_dpp(__float_as_int(v), 0x4E, 0xf, 0xf, true));
}

__device__ __forceinline__ void fence_bar() {
    asm volatile("" ::: "memory");
    __builtin_amdgcn_s_barrier();
    asm volatile("" ::: "memory");
}
#define LGKM0() asm volatile("s_waitcnt lgkmcnt(0)" ::: "memory")
#define VMCNT(n) asm volatile("s_waitcnt vmcnt(" #n ")" ::: "memory")

// ---------------- Kernel 1: x fp32 -> bf16 ----------------
__global__ __launch_bounds__(256) void conv_x(const float* __restrict__ x, short* __restrict__ xb) {
    const long long total = (long long)M_DIM * K_DIM;
    for (long long e0 = ((long long)blockIdx.x * 256 + threadIdx.x) * 8;
         e0 < total;
         e0 += (long long)gridDim.x * 256 * 8) {
        const float4* p = (const float4*)(x + e0);
        float4 v0 = p[0];
        float4 v1 = p[1];
        short8 s;
        s[0] = f2bf(v0.x); s[1] = f2bf(v0.y); s[2] = f2bf(v0.z); s[3] = f2bf(v0.w);
        s[4] = f2bf(v1.x); s[5] = f2bf(v1.y); s[6] = f2bf(v1.z); s[7] = f2bf(v1.w);
        *(short8*)(xb + e0) = s;
    }
}

// ---------------- Kernel 2: fused fake-quant + 256x256 8-phase bf16 GEMM, split-K ----------------
// A = xb [M,K] bf16 via global_load_lds (XOR-swizzled source) -- R4's proven path, unchanged.
// B = W [N,K] fp32, reg-staged as 2 chunks/tile (128 rows each); thread = quarter-row
// (16 floats). Group min/max = local tree + DPP quad xor1+xor2 (the 4 quarter-threads of a
// row share one quad) -- ZERO DS ops in quant, no in-order-lgkm coupling with phase ds_reads.
// 512 threads = 8 waves (2M x 4N); wave C = 128x64. LDS 128 KiB. Partials bf16.

template<int QD>
__device__ __forceinline__ void phase_reads(const short* __restrict__ Asd,
                                            const short* __restrict__ Bsd,
                                            int arow, int brow, int qb,
                                            bf16x8 (&af)[2][2], bf16x8 (&bfr)[2][4]) {
    if (QD == 0) {
        #pragma unroll
        for (int ks = 0; ks < 2; ++ks)
            #pragma unroll
            for (int fn = 0; fn < 4; ++fn) {
                const int r = brow + fn * 16;
                bfr[ks][fn] = *(const bf16x8*)&Bsd[r * 64 + (((ks * 4 + qb) ^ (r & 7)) * 8)];
            }
    }
    #pragma unroll
    for (int ks = 0; ks < 2; ++ks)
        #pragma unroll
        for (int j = 0; j < 2; ++j) {
            const int r = arow + (QD * 2 + j) * 16;
            af[ks][j] = *(const bf16x8*)&Asd[r * 64 + (((ks * 4 + qb) ^ (r & 7)) * 8)];
        }
}

template<int QD>
__device__ __forceinline__ void phase_mfma(const bf16x8 (&af)[2][2], const bf16x8 (&bfr)[2][4],
                                           f32x4 (&acc)[8][4]) {
    __builtin_amdgcn_s_setprio(1);
    #pragma unroll
    for (int ks = 0; ks < 2; ++ks)
        #pragma unroll
        for (int j = 0; j < 2; ++j)
            #pragma unroll
            for (int fn = 0; fn < 4; ++fn)
                acc[QD * 2 + j][fn] = __builtin_amdgcn_mfma_f32_16x16x32_bf16(
                    af[ks][j], bfr[ks][fn], acc[QD * 2 + j][fn], 0, 0, 0);
    __builtin_amdgcn_s_setprio(0);
}

__global__ __launch_bounds__(512, 2) void gemm_fq(const short* __restrict__ A,
                                                  const float* __restrict__ W,
                                                  unsigned short* __restrict__ P,
                                                  int spb) {
    __shared__ short As[2][256 * 64];
    __shared__ short Bs[2][256 * 64];
    const int tid  = threadIdx.x;
    const int lane = tid & 63;
    const int w    = tid >> 6;
    const int wr   = w >> 2;     // 0..1
    const int wc   = w & 3;      // 0..3
    const int m0   = blockIdx.y * 256;
    const int n0   = blockIdx.x * 256;
    const int kt0  = blockIdx.z * spb;
    const int kt1  = min(kt0 + spb, KSTEPS);   // every split >= 2 tiles by construction

    const int srow = tid >> 3;                       // 0..63  (A staging)
    const int sswz = (tid & 7) ^ (srow & 7);         // A staging source swizzle
    const int rC   = tid >> 2;                       // 0..127 row within a 128-row B chunk
    const int qC   = tid & 3;                        // quarter (16 floats) of the 64-group
    const int arow = wr * 128 + (lane & 15);
    const int brow = wc * 64 + (lane & 15);
    const int qb   = lane >> 4;

    f32x4  acc[8][4] = {};
    bf16x8 bfr[2][4];
    bf16x8 af[2][2];
    float4 C0[4], C1[4];   // two B-chunk reg sets (16 floats each), static indexing only

    auto stageA = [&](int d, int h, int kt) {
        #pragma unroll
        for (int l = 0; l < 2; ++l) {
            __builtin_amdgcn_global_load_lds(
                GLOBAL_AS(A + (size_t)(m0 + h * 128 + l * 64 + srow) * K_DIM + kt * 64 + sswz * 8),
                LDS_AS(&As[d][(h * 128 + l * 64 + w * 8) * 64]), 16, 0, 0);
        }
    };
    auto loadC = [&](float4 (&dst)[4], int c, int kt) {
        const float4* src = (const float4*)(W + (size_t)(n0 + c * 128 + rC) * K_DIM + (size_t)kt * 64 + qC * 16);
        #pragma unroll
        for (int j = 0; j < 4; ++j) dst[j] = src[j];
    };
    auto quantC = [&](const float4 (&v)[4], int c, short* BsF) {
        const float* pv = (const float*)&v[0];
        float mns[8], mxs[8];
        #pragma unroll
        for (int j = 0; j < 8; ++j) {
            mns[j] = fminf(pv[2 * j], pv[2 * j + 1]);
            mxs[j] = fmaxf(pv[2 * j], pv[2 * j + 1]);
        }
        #pragma unroll
        for (int st = 4; st >= 1; st >>= 1)
            #pragma unroll
            for (int j = 0; j < st; ++j) {
                mns[j] = fminf(mns[j], mns[j + st]);
                mxs[j] = fmaxf(mxs[j], mxs[j + st]);
            }
        // 4 quarter-threads of one row live in one DPP quad: pure-VALU group reduce
        float mn = fminf(mns[0], dpp_xor1(mns[0]));
        mn = fminf(mn, dpp_xor2(mn));
        float mx = fmaxf(mxs[0], dpp_xor1(mxs[0]));
        mx = fmaxf(mx, dpp_xor2(mx));
        float range = fmaxf(mx - mn, 1e-5f);
        float scale = range * (1.0f / 15.0f);
        float rs    = 1.0f / scale;   // one precise div per thread per chunk
        // clamp mathematically redundant: rint(mn*rs) = -zp, rint(mx*rs) = 15-zp (proven, R6 passed)
        const int r    = c * 128 + rC;
        const int base = r * 64;
        #pragma unroll
        for (int s4 = 0; s4 < 2; ++s4) {
            float q[8];
            #pragma unroll
            for (int j = 0; j < 8; ++j)
                q[j] = rintf(pv[s4 * 8 + j] * rs) * scale;
            union { unsigned u[4]; short8 s; } pk;
            #pragma unroll
            for (int j = 0; j < 4; ++j)
                pk.u[j] = cvt_pk_bf16(q[2 * j], q[2 * j + 1]);
            const int s = qC * 2 + s4;   // 8-elem slot 0..7
            *(short8*)&BsF[base + ((s ^ (r & 7)) * 8)] = pk.s;
        }
    };

    // ---- prologue: tile kt0 -> buf0; preload both chunks of kt0+1 ----
    loadC(C0, 0, kt0);                         // +4
    loadC(C1, 1, kt0);                         // +4
    stageA(0, 0, kt0);                         // +2
    stageA(0, 1, kt0);                         // +2
    VMCNT(8);  quantC(C0, 0, Bs[0]);           // c0(kt0) landed
    VMCNT(4);  quantC(C1, 1, Bs[0]);           // c1(kt0) landed (A:4 outstanding)
    loadC(C0, 0, kt0 + 1);                     // +4
    loadC(C1, 1, kt0 + 1);                     // +4
    VMCNT(8);                                  // A(kt0) landed; leaves [c0',c1'] = 8
    LGKM0();
    fence_bar();

    int par = 0;
    for (int t = kt0; t < kt1; ++t) {
        const int tn  = (t + 1 < kt1) ? t + 1 : t;        // A stage target (dummy on last)
        const int tn2 = (t + 2 < kt1) ? t + 2 : kt1 - 1;  // B chunk loads (dummy on tail)
        const short* Asc = As[par];
        const short* Bsc = Bs[par];
        short* Bsn = Bs[par ^ 1];
        // P0
        phase_reads<0>(Asc, Bsc, arow, brow, qb, af, bfr);
        VMCNT(4);                    // c0(t+1) landed (leaves c1(t+1):4)
        quantC(C0, 0, Bsn);
        stageA(par ^ 1, 0, tn);      // +2
        fence_bar(); LGKM0();
        phase_mfma<0>(af, bfr, acc);
        fence_bar();
        // P1
        phase_reads<1>(Asc, Bsc, arow, brow, qb, af, bfr);
        VMCNT(2);                    // c1(t+1) landed (leaves A h0:2)
        quantC(C1, 1, Bsn);
        stageA(par ^ 1, 1, tn);      // +2
        fence_bar(); LGKM0();
        phase_mfma<1>(af, bfr, acc);
        fence_bar();
        // P2
        phase_reads<2>(Asc, Bsc, arow, brow, qb, af, bfr);
        loadC(C0, 0, tn2);           // +4
        fence_bar(); LGKM0();
        phase_mfma<2>(af, bfr, acc);
        fence_bar();
        // P3
        phase_reads<3>(Asc, Bsc, arow, brow, qb, af, bfr);
        loadC(C1, 1, tn2);           // +4
        fence_bar(); LGKM0();
        phase_mfma<3>(af, bfr, acc);
        VMCNT(8);                    // A(t+1) landed; leaves [c0'',c1''] = 8
        fence_bar();
        par ^= 1;
    }

    VMCNT(0);   // drain dummy tail loads

    unsigned short* out = P + (size_t)blockIdx.z * M_DIM * N_DIM;
    #pragma unroll
    for (int fm = 0; fm < 8; ++fm) {
        #pragma unroll
        for (int fn = 0; fn < 4; ++fn) {
            const int col  = n0 + wc * 64 + fn * 16 + (lane & 15);
            const int rowb = m0 + wr * 128 + fm * 16 + (lane >> 4) * 4;
            #pragma unroll
            for (int r = 0; r < 4; ++r) {
                out[(size_t)(rowb + r) * N_DIM + col] = (unsigned short)f2bf(acc[fm][fn][r]);
            }
        }
    }
}

// ---------------- Kernel 3: reduce bf16 split-K partials + bias ----------------
__global__ __launch_bounds__(256) void reduce_out(const unsigned short* __restrict__ P,
                                                  const float* __restrict__ bias,
                                                  float* __restrict__ out,
                                                  int splitk) {
    const size_t total = (size_t)M_DIM * N_DIM;
    for (size_t idx8 = ((size_t)blockIdx.x * 256 + threadIdx.x) * 8;
         idx8 < total;
         idx8 += (size_t)gridDim.x * 256 * 8) {
        const int col = (int)(idx8 % N_DIM);
        float s[8];
        {
            float4 b0 = *(const float4*)(bias + col);
            float4 b1 = *(const float4*)(bias + col + 4);
            s[0] = b0.x; s[1] = b0.y; s[2] = b0.z; s[3] = b0.w;
            s[4] = b1.x; s[5] = b1.y; s[6] = b1.z; s[7] = b1.w;
        }
        for (int sp = 0; sp < splitk; ++sp) {
            short8 p = *(const short8*)(P + (size_t)sp * total + idx8);
            #pragma unroll
            for (int j = 0; j < 8; ++j)
                s[j] += __uint_as_float(((unsigned)(unsigned short)p[j]) << 16);
        }
        float4 o0 = {s[0], s[1], s[2], s[3]};
        float4 o1 = {s[4], s[5], s[6], s[7]};
        *(float4*)(out + idx8) = o0;
        *(float4*)(out + idx8 + 4) = o1;
    }
}

extern "C" void kernel_launch(void* const* d_in, const int* in_sizes, int n_in,
                              void* d_out, int out_size, void* d_ws, size_t ws_size,
                              hipStream_t stream) {
    const float* x    = (const float*)d_in[0];
    const float* wgt  = (const float*)d_in[1];
    const float* bias = (const float*)d_in[2];
    float* out = (float*)d_out;

    char* ws = (char*)d_ws;
    const size_t xb_bytes = (size_t)M_DIM * K_DIM * 2;          // 11,272,192
    short* xb = (short*)ws;
    unsigned short* part = (unsigned short*)(ws + xb_bytes);

    const size_t per_split = (size_t)M_DIM * N_DIM * 2;         // 4 MiB (bf16)
    size_t avail = (ws_size > xb_bytes) ? (ws_size - xb_bytes) : 0;
    // largest splitk in [1,8] that fits, with every split >= 2 K-tiles
    int splitk = 1, spb = KSTEPS;
    for (int sk = 8; sk >= 1; --sk) {
        if ((size_t)sk * per_split > avail) continue;
        int s = (KSTEPS + sk - 1) / sk;
        int last = KSTEPS - (sk - 1) * s;
        if (last < 2) continue;
        splitk = sk; spb = s;
        break;
    }

    hipLaunchKernelGGL(conv_x, dim3(2048), dim3(256), 0, stream, x, xb);
    hipLaunchKernelGGL(gemm_fq, dim3(N_DIM / 256, M_DIM / 256, splitk), dim3(512), 0, stream,
                       xb, wgt, part, spb);
    hipLaunchKernelGGL(reduce_out, dim3(1024), dim3(256), 0, stream, part, bias, out, splitk);
}

// Round 8
// 92.325 us; speedup vs baseline: 1.8567x; 1.0681x over previous
//
#include <hip/hip_runtime.h>
#include <hip/hip_bf16.h>
#include <stdint.h>

typedef __attribute__((ext_vector_type(8))) short bf16x8;
typedef __attribute__((ext_vector_type(8))) short short8;
typedef __attribute__((ext_vector_type(4))) float f32x4;

#define M_DIM 512
#define N_DIM 4096
#define K_DIM 11008
#define KSTEPS 172   // K_DIM / 64

#define GLOBAL_AS(p) ((const __attribute__((address_space(1))) void*)(p))
#define LDS_AS(p)    ((__attribute__((address_space(3))) void*)(p))

// round-to-nearest-even fp32 -> bf16 bits
__device__ __forceinline__ short f2bf(float f) {
    unsigned u = __float_as_uint(f);
    unsigned r = u + 0x7fff + ((u >> 16) & 1);
    return (short)(r >> 16);
}

__device__ __forceinline__ unsigned cvt_pk_bf16(float lo, float hi) {
    unsigned r;
    asm("v_cvt_pk_bf16_f32 %0, %1, %2" : "=v"(r) : "v"(lo), "v"(hi));
    return r;
}

// quad_perm lane exchanges (pure VALU, no DS)
__device__ __forceinline__ float dpp_xor1(float v) {
    return __int_as_float(__builtin_amdgcn_mov_dpp(__float_as_int(v), 0xB1, 0xf, 0xf, true));
}
__device__ __forceinline__ float dpp_xor2(float v) {
    return __int_as_float(__builtin_amdgcn_mov_dpp(__float_as_int(v), 0x4E, 0xf, 0xf, true));
}

__device__ __forceinline__ void fence_bar() {
    asm volatile("" ::: "memory");
    __builtin_amdgcn_s_barrier();
    asm volatile("" ::: "memory");
}
#define LGKM0() asm volatile("s_waitcnt lgkmcnt(0)" ::: "memory")
#define VMCNT(n) asm volatile("s_waitcnt vmcnt(" #n ")" ::: "memory")

// ---------------- Kernel 1: x fp32 -> bf16 ----------------
__global__ __launch_bounds__(256) void conv_x(const float* __restrict__ x, short* __restrict__ xb) {
    const long long total = (long long)M_DIM * K_DIM;
    for (long long e0 = ((long long)blockIdx.x * 256 + threadIdx.x) * 8;
         e0 < total;
         e0 += (long long)gridDim.x * 256 * 8) {
        const float4* p = (const float4*)(x + e0);
        float4 v0 = p[0];
        float4 v1 = p[1];
        short8 s;
        s[0] = f2bf(v0.x); s[1] = f2bf(v0.y); s[2] = f2bf(v0.z); s[3] = f2bf(v0.w);
        s[4] = f2bf(v1.x); s[5] = f2bf(v1.y); s[6] = f2bf(v1.z); s[7] = f2bf(v1.w);
        *(short8*)(xb + e0) = s;
    }
}

// ---------------- Kernel 2: fused fake-quant + 256x256 bf16 GEMM, ONE barrier per K-tile ----------------
// Strict 2-buffer alternation: within tile t, ALL LDS reads hit buf[par], ALL writes
// (quant ds_writes + A global_load_lds) hit buf[par^1] -> a single barrier per tile suffices.
// All 64 MFMAs per wave in one region; compiler schedules ds_read/MFMA interleave (auto lgkmcnt)
// and quant VALU issues under the MFMA pipe. Manual vmcnt only for A staging ledger.
// A = xb [M,K] bf16 via global_load_lds (XOR-swizzled source).
// B = W [N,K] fp32, reg-staged 2 chunks x 128 rows (thread = quarter-row, 16 floats);
// group reduce = local tree + DPP quad xor1/xor2 (zero DS). 512 thr = 8 waves; wave C = 128x64.
__global__ __launch_bounds__(512, 2) void gemm_fq(const short* __restrict__ A,
                                                  const float* __restrict__ W,
                                                  unsigned short* __restrict__ P,
                                                  int spb) {
    __shared__ short As[2][256 * 64];
    __shared__ short Bs[2][256 * 64];
    const int tid  = threadIdx.x;
    const int lane = tid & 63;
    const int w    = tid >> 6;
    const int wr   = w >> 2;     // 0..1
    const int wc   = w & 3;      // 0..3
    const int m0   = blockIdx.y * 256;
    const int n0   = blockIdx.x * 256;
    const int kt0  = blockIdx.z * spb;
    const int kt1  = min(kt0 + spb, KSTEPS);   // every split >= 2 tiles by construction

    const int srow = tid >> 3;                       // 0..63  (A staging)
    const int sswz = (tid & 7) ^ (srow & 7);         // A staging source swizzle
    const int rC   = tid >> 2;                       // 0..127 row within a 128-row B chunk
    const int qC   = tid & 3;                        // quarter (16 floats) of the 64-group
    const int arow = wr * 128 + (lane & 15);
    const int brow = wc * 64 + (lane & 15);
    const int qb   = lane >> 4;

    f32x4  acc[8][4] = {};
    float4 C0[4], C1[4];   // B-chunk reg sets (16 floats each), static indexing only

    auto stageA = [&](int d, int h, int kt) {
        #pragma unroll
        for (int l = 0; l < 2; ++l) {
            __builtin_amdgcn_global_load_lds(
                GLOBAL_AS(A + (size_t)(m0 + h * 128 + l * 64 + srow) * K_DIM + kt * 64 + sswz * 8),
                LDS_AS(&As[d][(h * 128 + l * 64 + w * 8) * 64]), 16, 0, 0);
        }
    };
    auto loadC = [&](float4 (&dst)[4], int c, int kt) {
        const float4* src = (const float4*)(W + (size_t)(n0 + c * 128 + rC) * K_DIM + (size_t)kt * 64 + qC * 16);
        #pragma unroll
        for (int j = 0; j < 4; ++j) dst[j] = src[j];
    };
    auto quantC = [&](const float4 (&v)[4], int c, short* BsF) {
        const float* pv = (const float*)&v[0];
        float mns[8], mxs[8];
        #pragma unroll
        for (int j = 0; j < 8; ++j) {
            mns[j] = fminf(pv[2 * j], pv[2 * j + 1]);
            mxs[j] = fmaxf(pv[2 * j], pv[2 * j + 1]);
        }
        #pragma unroll
        for (int st = 4; st >= 1; st >>= 1)
            #pragma unroll
            for (int j = 0; j < st; ++j) {
                mns[j] = fminf(mns[j], mns[j + st]);
                mxs[j] = fmaxf(mxs[j], mxs[j + st]);
            }
        // 4 quarter-threads of one row live in one DPP quad: pure-VALU group reduce
        float mn = fminf(mns[0], dpp_xor1(mns[0]));
        mn = fminf(mn, dpp_xor2(mn));
        float mx = fmaxf(mxs[0], dpp_xor1(mxs[0]));
        mx = fmaxf(mx, dpp_xor2(mx));
        float range = fmaxf(mx - mn, 1e-5f);
        float scale = range * (1.0f / 15.0f);
        float rs    = 1.0f / scale;   // one precise div per thread per chunk
        // zero-point cancels: w_dq = rint(w/s)*s when no clipping; clamp redundant (proven R6/R7)
        const int r    = c * 128 + rC;
        const int base = r * 64;
        #pragma unroll
        for (int s4 = 0; s4 < 2; ++s4) {
            float q[8];
            #pragma unroll
            for (int j = 0; j < 8; ++j)
                q[j] = rintf(pv[s4 * 8 + j] * rs) * scale;
            union { unsigned u[4]; short8 s; } pk;
            #pragma unroll
            for (int j = 0; j < 4; ++j)
                pk.u[j] = cvt_pk_bf16(q[2 * j], q[2 * j + 1]);
            const int s = qC * 2 + s4;   // 8-elem slot 0..7
            *(short8*)&BsF[base + ((s ^ (r & 7)) * 8)] = pk.s;
        }
    };

    // ---- prologue: tile kt0 quantized into buf0; A(kt0) -> As[0]; preload C(kt0+1) ----
    loadC(C0, 0, kt0);                         // +4
    loadC(C1, 1, kt0);                         // +4
    stageA(0, 0, kt0);                         // +2
    stageA(0, 1, kt0);                         // +2
    VMCNT(8);  quantC(C0, 0, Bs[0]);           // C0(kt0) landed
    VMCNT(4);  quantC(C1, 1, Bs[0]);           // C1(kt0) landed (A:4 outstanding)
    loadC(C0, 0, kt0 + 1);                     // +4
    loadC(C1, 1, kt0 + 1);                     // +4
    VMCNT(8);                                  // A(kt0) landed; queue = [C':8]
    LGKM0();
    fence_bar();

    int par = 0;
    for (int t = kt0; t < kt1; ++t) {
        const int tn  = (t + 1 < kt1) ? t + 1 : t;        // A stage target (dummy on last)
        const int tn2 = (t + 2 < kt1) ? t + 2 : kt1 - 1;  // C loads (dummy on tail)
        const short* Asc = As[par];
        const short* Bsc = Bs[par];
        short* Bsn = Bs[par ^ 1];

        // ---- one region per tile: reads + 64 MFMA + quant + stage, compiler-scheduled ----
        bf16x8 bfr[2][4];
        #pragma unroll
        for (int ks = 0; ks < 2; ++ks)
            #pragma unroll
            for (int fn = 0; fn < 4; ++fn) {
                const int r = brow + fn * 16;
                bfr[ks][fn] = *(const bf16x8*)&Bsc[r * 64 + (((ks * 4 + qb) ^ (r & 7)) * 8)];
            }
        #pragma unroll
        for (int qd = 0; qd < 4; ++qd) {
            bf16x8 af[2][2];
            #pragma unroll
            for (int ks = 0; ks < 2; ++ks)
                #pragma unroll
                for (int j = 0; j < 2; ++j) {
                    const int r = arow + (qd * 2 + j) * 16;
                    af[ks][j] = *(const bf16x8*)&Asc[r * 64 + (((ks * 4 + qb) ^ (r & 7)) * 8)];
                }
            #pragma unroll
            for (int ks = 0; ks < 2; ++ks)
                #pragma unroll
                for (int j = 0; j < 2; ++j)
                    #pragma unroll
                    for (int fn = 0; fn < 4; ++fn)
                        acc[qd * 2 + j][fn] = __builtin_amdgcn_mfma_f32_16x16x32_bf16(
                            af[ks][j], bfr[ks][fn], acc[qd * 2 + j][fn], 0, 0, 0);
        }
        // quant tile t+1's B (C regs issued a full tile ago; compiler auto-waits vmcnt)
        quantC(C0, 0, Bsn);
        quantC(C1, 1, Bsn);
        // stage A(t+1), then refill C with tile t+2
        stageA(par ^ 1, 0, tn);      // +2
        stageA(par ^ 1, 1, tn);      // +2
        loadC(C0, 0, tn2);           // +4
        loadC(C1, 1, tn2);           // +4
        VMCNT(8);                    // A(t+1) landed; queue = [C'':8]
        LGKM0();                     // quant ds_writes (and any reads) drained
        fence_bar();
        par ^= 1;
    }

    VMCNT(0);   // drain dummy tail loads

    unsigned short* out = P + (size_t)blockIdx.z * M_DIM * N_DIM;
    #pragma unroll
    for (int fm = 0; fm < 8; ++fm) {
        #pragma unroll
        for (int fn = 0; fn < 4; ++fn) {
            const int col  = n0 + wc * 64 + fn * 16 + (lane & 15);
            const int rowb = m0 + wr * 128 + fm * 16 + (lane >> 4) * 4;
            #pragma unroll
            for (int r = 0; r < 4; ++r) {
                out[(size_t)(rowb + r) * N_DIM + col] = (unsigned short)f2bf(acc[fm][fn][r]);
            }
        }
    }
}

// ---------------- Kernel 3: reduce bf16 split-K partials + bias ----------------
__global__ __launch_bounds__(256) void reduce_out(const unsigned short* __restrict__ P,
                                                  const float* __restrict__ bias,
                                                  float* __restrict__ out,
                                                  int splitk) {
    const size_t total = (size_t)M_DIM * N_DIM;
    for (size_t idx8 = ((size_t)blockIdx.x * 256 + threadIdx.x) * 8;
         idx8 < total;
         idx8 += (size_t)gridDim.x * 256 * 8) {
        const int col = (int)(idx8 % N_DIM);
        float s[8];
        {
            float4 b0 = *(const float4*)(bias + col);
            float4 b1 = *(const float4*)(bias + col + 4);
            s[0] = b0.x; s[1] = b0.y; s[2] = b0.z; s[3] = b0.w;
            s[4] = b1.x; s[5] = b1.y; s[6] = b1.z; s[7] = b1.w;
        }
        for (int sp = 0; sp < splitk; ++sp) {
            short8 p = *(const short8*)(P + (size_t)sp * total + idx8);
            #pragma unroll
            for (int j = 0; j < 8; ++j)
                s[j] += __uint_as_float(((unsigned)(unsigned short)p[j]) << 16);
        }
        float4 o0 = {s[0], s[1], s[2], s[3]};
        float4 o1 = {s[4], s[5], s[6], s[7]};
        *(float4*)(out + idx8) = o0;
        *(float4*)(out + idx8 + 4) = o1;
    }
}

extern "C" void kernel_launch(void* const* d_in, const int* in_sizes, int n_in,
                              void* d_out, int out_size, void* d_ws, size_t ws_size,
                              hipStream_t stream) {
    const float* x    = (const float*)d_in[0];
    const float* wgt  = (const float*)d_in[1];
    const float* bias = (const float*)d_in[2];
    float* out = (float*)d_out;

    char* ws = (char*)d_ws;
    const size_t xb_bytes = (size_t)M_DIM * K_DIM * 2;          // 11,272,192
    short* xb = (short*)ws;
    unsigned short* part = (unsigned short*)(ws + xb_bytes);

    const size_t per_split = (size_t)M_DIM * N_DIM * 2;         // 4 MiB (bf16)
    size_t avail = (ws_size > xb_bytes) ? (ws_size - xb_bytes) : 0;
    // largest splitk in [1,8] that fits, with every split >= 2 K-tiles
    int splitk = 1, spb = KSTEPS;
    for (int sk = 8; sk >= 1; --sk) {
        if ((size_t)sk * per_split > avail) continue;
        int s = (KSTEPS + sk - 1) / sk;
        int last = KSTEPS - (sk - 1) * s;
        if (last < 2) continue;
        splitk = sk; spb = s;
        break;
    }

    hipLaunchKernelGGL(conv_x, dim3(2048), dim3(256), 0, stream, x, xb);
    hipLaunchKernelGGL(gemm_fq, dim3(N_DIM / 256, M_DIM / 256, splitk), dim3(512), 0, stream,
                       xb, wgt, part, spb);
    hipLaunchKernelGGL(reduce_out, dim3(1024), dim3(256), 0, stream, part, bias, out, splitk);
}